// Round 4
// baseline (111.405 us; speedup 1.0000x reference)
//
#include <hip/hip_runtime.h>
#include <math.h>

// Problem constants (fixed by reference): N=32, RES=256, C=2, K=1024, T=1, EPS=1e-6
constexpr int   N_   = 32;
constexpr int   RES_ = 256;
constexpr int   K_   = 1024;
constexpr float EPS_ = 1e-6f;
constexpr float LOG2E_ = 1.44269504088896340736f;
constexpr float LN2_   = 0.69314718055994530942f;

constexpr int BLK_PER_N = 16;               // j-slabs of 64 per image
constexpr int NBLK      = N_ * BLK_PER_N;   // 512 blocks
constexpr int NTHR      = 512;              // 8 waves/block

// ---------------------------------------------------------------------------
// Bilinear sample (grid_sample, zeros padding, align_corners=True, pixel coords)
// ---------------------------------------------------------------------------
__device__ __forceinline__ float2 gather_tex(const float* __restrict__ base, int xi, int yi) {
    bool valid = (xi >= 0) & (xi <= RES_ - 1) & (yi >= 0) & (yi <= RES_ - 1);
    int xc = min(max(xi, 0), RES_ - 1);
    int yc = min(max(yi, 0), RES_ - 1);
    float2 v = *reinterpret_cast<const float2*>(base + ((size_t)yc * RES_ + xc) * 2);
    float m = valid ? 1.0f : 0.0f;
    v.x *= m; v.y *= m;
    return v;
}

__device__ __forceinline__ float2 sample_one(const float* __restrict__ base, float2 p) {
    float x0f = floorf(p.x), y0f = floorf(p.y);
    float wx = p.x - x0f,    wy = p.y - y0f;
    int x0 = (int)x0f, y0 = (int)y0f;
    float2 v00 = gather_tex(base, x0,     y0);
    float2 v10 = gather_tex(base, x0 + 1, y0);
    float2 v01 = gather_tex(base, x0,     y0 + 1);
    float2 v11 = gather_tex(base, x0 + 1, y0 + 1);
    float w00 = (1.0f - wx) * (1.0f - wy);
    float w10 = wx * (1.0f - wy);
    float w01 = (1.0f - wx) * wy;
    float w11 = wx * wy;
    float2 o;
    o.x = v00.x * w00 + v10.x * w10 + v01.x * w01 + v11.x * w11;
    o.y = v00.y * w00 + v10.y * w10 + v01.y * w01 + v11.y * w11;
    return o;
}

// ---------------------------------------------------------------------------
// Pre-kernel: sample ALL keypoints (src and trg, each once) into ws, scaled by
// log2(e). Also zero-inits the accumulators (ws is poisoned 0xAA each call).
// gid < N*K -> src point; else trg point. Block-aligned split (no divergence).
// ---------------------------------------------------------------------------
__global__ void __launch_bounds__(256) sample_kernel(
        const float* __restrict__ src_flow, const float* __restrict__ trg_flow,
        const float* __restrict__ src_kp,   const float* __restrict__ trg_kp,
        float2* __restrict__ src_c, float2* __restrict__ trg_c,
        float* __restrict__ accum, int* __restrict__ flag) {
    int gid = blockIdx.x * 256 + threadIdx.x;       // 0 .. 2*N*K-1
    bool is_trg = gid >= N_ * K_;
    int idx = is_trg ? gid - N_ * K_ : gid;
    int n = idx >> 10;                              // K = 1024
    const float* flow = is_trg ? trg_flow : src_flow;
    const float2* kp  = reinterpret_cast<const float2*>(is_trg ? trg_kp : src_kp);
    float2 v = sample_one(flow + (size_t)n * RES_ * RES_ * 2, kp[idx]);
    v.x *= LOG2E_; v.y *= LOG2E_;
    (is_trg ? trg_c : src_c)[idx] = v;
    if (gid == 0) { accum[0] = 0.0f; accum[1] = 0.0f; *flag = 0; }
}

// ---------------------------------------------------------------------------
// Loss kernel. Coords pre-scaled by log2(e), so with r = log2e*dist:
//   contrib[j] = 2*ln2*(log2(sum_i 2^-r_ij) + r_jj) * vis * wt
// Wave w of 8 handles i-chunk [w*128, w*128+128); lane = j. LDS inner reads
// are wave-broadcast ds_read_b128 (conflict-free). Last block (fence+ticket)
// performs the final division -> no separate finalize dispatch.
// ---------------------------------------------------------------------------
__global__ void __launch_bounds__(NTHR) fused_loss_kernel(
        const float2* __restrict__ src_c, const float2* __restrict__ trg_c,
        const int*   __restrict__ kp_vis, const float* __restrict__ kp_wt,
        float* __restrict__ accum, int* __restrict__ flag,
        float* __restrict__ out) {
    __shared__ __align__(16) float4 s_src[K_ / 2];  // 8 KB (2 points per float4)
    __shared__ float s_part[8][64];                 // 2 KB

    const int blk   = blockIdx.x;
    const int n     = blk >> 4;                     // 16 blocks per n
    const int jbase = (blk & 15) * 64;
    const int t     = threadIdx.x;
    const int wave  = t >> 6;
    const int lane  = t & 63;

    // Stage src_c[n]: one coalesced float4 per thread (512 * 16B = 8 KB).
    const float4* g4 = reinterpret_cast<const float4*>(src_c + (size_t)n * K_);
    s_src[t] = g4[t];

    const int j  = jbase + lane;
    const int gj = n * K_ + j;
    float2 tc = trg_c[gj];                          // coalesced 8B loads
    const float tx = tc.x - LOG2E_ * EPS_;          // fold +eps into target
    const float ty = tc.y - LOG2E_ * EPS_;

    __syncthreads();

    // 128 i's per wave = 64 broadcast float4 reads.
    float s0 = 0.0f, s1 = 0.0f;
    #pragma unroll 8
    for (int k2 = 0; k2 < 64; ++k2) {
        float4 p = s_src[wave * 64 + k2];
        float dx0 = p.x - tx, dy0 = p.y - ty;
        float dx1 = p.z - tx, dy1 = p.w - ty;
        float r0 = __builtin_amdgcn_sqrtf(dx0 * dx0 + dy0 * dy0);
        float r1 = __builtin_amdgcn_sqrtf(dx1 * dx1 + dy1 * dy1);
        s0 += __builtin_amdgcn_exp2f(-r0);
        s1 += __builtin_amdgcn_exp2f(-r1);
    }
    s_part[wave][lane] = s0 + s1;
    __syncthreads();

    if (wave == 0) {
        float ssum = 0.0f;
        #pragma unroll
        for (int w = 0; w < 8; ++w) ssum += s_part[w][lane];
        float2 sj = reinterpret_cast<const float2*>(s_src)[j];
        float dxj = sj.x - tx, dyj = sj.y - ty;
        float rjj = __builtin_amdgcn_sqrtf(dxj * dxj + dyj * dyj);
        float visf = kp_vis[gj] ? 1.0f : 0.0f;
        float contrib = (2.0f * LN2_) * (__builtin_amdgcn_logf(ssum) + rjj)
                        * visf * kp_wt[gj];
        float cnt = visf;
        #pragma unroll
        for (int off = 32; off > 0; off >>= 1) {
            contrib += __shfl_down(contrib, off);
            cnt     += __shfl_down(cnt, off);
        }
        if (lane == 0) {
            atomicAdd(&accum[0], contrib);
            atomicAdd(&accum[1], cnt);
            __threadfence();
            int ticket = __hip_atomic_fetch_add(flag, 1, __ATOMIC_ACQ_REL,
                                                __HIP_MEMORY_SCOPE_AGENT);
            if (ticket == NBLK - 1) {
                float v = __hip_atomic_load(&accum[0], __ATOMIC_RELAXED,
                                            __HIP_MEMORY_SCOPE_AGENT);
                float c = __hip_atomic_load(&accum[1], __ATOMIC_RELAXED,
                                            __HIP_MEMORY_SCOPE_AGENT);
                out[0] = v / c;
            }
        }
    }
}

// ---------------------------------------------------------------------------
extern "C" void kernel_launch(void* const* d_in, const int* in_sizes, int n_in,
                              void* d_out, int out_size, void* d_ws, size_t ws_size,
                              hipStream_t stream) {
    const float* src_flow = (const float*)d_in[0];
    const float* trg_flow = (const float*)d_in[1];
    const float* src_kp   = (const float*)d_in[2];
    const float* trg_kp   = (const float*)d_in[3];
    const int*   kp_vis   = (const int*)d_in[4];
    const float* kp_wt    = (const float*)d_in[5];
    float* out = (float*)d_out;

    // ws layout: [accum(2 floats) | flag(int) | pad | src_c | trg_c]
    float*  ws    = (float*)d_ws;
    float*  accum = ws;
    int*    flag  = (int*)(ws + 2);
    float2* src_c = (float2*)(ws + 8);               // 32B offset, 16B-aligned
    float2* trg_c = src_c + (size_t)N_ * K_;

    sample_kernel<<<(2 * N_ * K_) / 256, 256, 0, stream>>>(
        src_flow, trg_flow, src_kp, trg_kp, src_c, trg_c, accum, flag);
    fused_loss_kernel<<<NBLK, NTHR, 0, stream>>>(
        src_c, trg_c, kp_vis, kp_wt, accum, flag, out);
}

// Round 5
// 97.819 us; speedup vs baseline: 1.1389x; 1.1389x over previous
//
#include <hip/hip_runtime.h>
#include <math.h>

// Problem constants (fixed by reference): N=32, RES=256, C=2, K=1024, T=1, EPS=1e-6
constexpr int   N_   = 32;
constexpr int   RES_ = 256;
constexpr int   K_   = 1024;
constexpr float EPS_ = 1e-6f;
constexpr float LOG2E_ = 1.44269504088896340736f;
constexpr float LN2_   = 0.69314718055994530942f;

constexpr int BLK_PER_N = 16;               // j-slabs of 64 per image
constexpr int NBLK      = N_ * BLK_PER_N;   // 512 blocks
constexpr int NTHR      = 512;              // 8 waves/block

// ---------------------------------------------------------------------------
// Bilinear sample (grid_sample, zeros padding, align_corners=True, pixel coords)
// ---------------------------------------------------------------------------
__device__ __forceinline__ float2 gather_tex(const float* __restrict__ base, int xi, int yi) {
    bool valid = (xi >= 0) & (xi <= RES_ - 1) & (yi >= 0) & (yi <= RES_ - 1);
    int xc = min(max(xi, 0), RES_ - 1);
    int yc = min(max(yi, 0), RES_ - 1);
    float2 v = *reinterpret_cast<const float2*>(base + ((size_t)yc * RES_ + xc) * 2);
    float m = valid ? 1.0f : 0.0f;
    v.x *= m; v.y *= m;
    return v;
}

__device__ __forceinline__ float2 sample_one(const float* __restrict__ base, float2 p) {
    float x0f = floorf(p.x), y0f = floorf(p.y);
    float wx = p.x - x0f,    wy = p.y - y0f;
    int x0 = (int)x0f, y0 = (int)y0f;
    float2 v00 = gather_tex(base, x0,     y0);
    float2 v10 = gather_tex(base, x0 + 1, y0);
    float2 v01 = gather_tex(base, x0,     y0 + 1);
    float2 v11 = gather_tex(base, x0 + 1, y0 + 1);
    float w00 = (1.0f - wx) * (1.0f - wy);
    float w10 = wx * (1.0f - wy);
    float w01 = (1.0f - wx) * wy;
    float w11 = wx * wy;
    float2 o;
    o.x = v00.x * w00 + v10.x * w10 + v01.x * w01 + v11.x * w11;
    o.y = v00.y * w00 + v10.y * w10 + v01.y * w01 + v11.y * w11;
    return o;
}

// ---------------------------------------------------------------------------
// Fused kernel (R3 structure — NO device-scope fences; they cost +14us in R4).
// Coords pre-scaled by log2(e), so with r = log2e*dist:
//   contrib[j] = 2*ln2*(log2(sum_i 2^-r_ij) + r_jj) * vis * wt
// Wave w of 8 handles i-chunk [w*128, w*128+128); lane = j. Inner LDS reads
// are wave-broadcast ds_read_b128 (conflict-free). trg samples de-duplicated
// via a 64-entry LDS array (was 8x redundant). vis/wt prefetched at entry.
// ---------------------------------------------------------------------------
__global__ void __launch_bounds__(NTHR) fused_loss_kernel(
        const float* __restrict__ src_flow, const float* __restrict__ trg_flow,
        const float* __restrict__ src_kp,   const float* __restrict__ trg_kp,
        const int*   __restrict__ kp_vis,   const float* __restrict__ kp_wt,
        float2* __restrict__ partials) {
    __shared__ __align__(16) float4 s_src[K_ / 2];  // 8 KB (2 points per float4)
    __shared__ float2 s_trg[64];                    // this block's 64 trg samples
    __shared__ float  s_part[8][64];                // 2 KB

    const int blk   = blockIdx.x;
    const int n     = blk >> 4;                     // 16 blocks per n
    const int jbase = (blk & 15) * 64;
    const int t     = threadIdx.x;
    const int wave  = t >> 6;
    const int lane  = t & 63;
    const int j     = jbase + lane;
    const int gj    = n * K_ + j;

    // Prefetch vis/wt now (used only in the wave-0 tail; hide ~900cy latency).
    const float visf = kp_vis[gj] ? 1.0f : 0.0f;
    const float wtv  = kp_wt[gj];

    // Stage log2e * src_c[n][0..K) into LDS: 512 threads x 2 keypoints.
    float2* s_src2 = reinterpret_cast<float2*>(s_src);
    const float2* skp  = reinterpret_cast<const float2*>(src_kp) + (size_t)n * K_;
    const float* sbase = src_flow + (size_t)n * RES_ * RES_ * 2;
    #pragma unroll
    for (int k = t; k < K_; k += NTHR) {
        float2 v = sample_one(sbase, skp[k]);
        v.x *= LOG2E_; v.y *= LOG2E_;
        s_src2[k] = v;
    }
    // Sample this block's 64 trg keypoints ONCE (threads 0..63).
    if (t < 64) {
        const float2* tkp  = reinterpret_cast<const float2*>(trg_kp) + (size_t)n * K_;
        const float* tbase = trg_flow + (size_t)n * RES_ * RES_ * 2;
        float2 v = sample_one(tbase, tkp[jbase + t]);
        v.x *= LOG2E_; v.y *= LOG2E_;
        s_trg[t] = v;
    }
    __syncthreads();

    float2 tc = s_trg[lane];
    const float tx = tc.x - LOG2E_ * EPS_;          // fold +eps into target
    const float ty = tc.y - LOG2E_ * EPS_;

    // 128 i's per wave = 64 broadcast float4 reads.
    float s0 = 0.0f, s1 = 0.0f;
    #pragma unroll 8
    for (int k2 = 0; k2 < 64; ++k2) {
        float4 p = s_src[wave * 64 + k2];
        float dx0 = p.x - tx, dy0 = p.y - ty;
        float dx1 = p.z - tx, dy1 = p.w - ty;
        float r0 = __builtin_amdgcn_sqrtf(dx0 * dx0 + dy0 * dy0);
        float r1 = __builtin_amdgcn_sqrtf(dx1 * dx1 + dy1 * dy1);
        s0 += __builtin_amdgcn_exp2f(-r0);
        s1 += __builtin_amdgcn_exp2f(-r1);
    }
    s_part[wave][lane] = s0 + s1;
    __syncthreads();

    if (wave == 0) {
        float ssum = 0.0f;
        #pragma unroll
        for (int w = 0; w < 8; ++w) ssum += s_part[w][lane];
        float2 sj = s_src2[j];
        float dxj = sj.x - tx, dyj = sj.y - ty;
        float rjj = __builtin_amdgcn_sqrtf(dxj * dxj + dyj * dyj);
        float contrib = (2.0f * LN2_) * (__builtin_amdgcn_logf(ssum) + rjj)
                        * visf * wtv;
        float cnt = visf;
        #pragma unroll
        for (int off = 32; off > 0; off >>= 1) {
            contrib += __shfl_down(contrib, off);
            cnt     += __shfl_down(cnt, off);
        }
        if (lane == 0) partials[blk] = make_float2(contrib, cnt);
    }
}

// ---------------------------------------------------------------------------
// Sum 512 (loss, cnt) pairs, divide. One wave, no LDS, no barrier.
// ---------------------------------------------------------------------------
__global__ void __launch_bounds__(64) finalize_kernel(const float2* __restrict__ partials,
                                                      float* __restrict__ out) {
    const int t = threadIdx.x;
    float v = 0.0f, c = 0.0f;
    #pragma unroll
    for (int b = t; b < NBLK; b += 64) {
        float2 p = partials[b];
        v += p.x; c += p.y;
    }
    #pragma unroll
    for (int off = 32; off > 0; off >>= 1) {
        v += __shfl_down(v, off);
        c += __shfl_down(c, off);
    }
    if (t == 0) out[0] = v / c;
}

// ---------------------------------------------------------------------------
extern "C" void kernel_launch(void* const* d_in, const int* in_sizes, int n_in,
                              void* d_out, int out_size, void* d_ws, size_t ws_size,
                              hipStream_t stream) {
    const float* src_flow = (const float*)d_in[0];
    const float* trg_flow = (const float*)d_in[1];
    const float* src_kp   = (const float*)d_in[2];
    const float* trg_kp   = (const float*)d_in[3];
    const int*   kp_vis   = (const int*)d_in[4];
    const float* kp_wt    = (const float*)d_in[5];
    float* out = (float*)d_out;

    float2* partials = (float2*)d_ws;        // [NBLK], fully overwritten each call

    fused_loss_kernel<<<NBLK, NTHR, 0, stream>>>(src_flow, trg_flow, src_kp, trg_kp,
                                                 kp_vis, kp_wt, partials);
    finalize_kernel<<<1, 64, 0, stream>>>(partials, out);
}